// Round 1
// baseline (452.102 us; speedup 1.0000x reference)
//
#include <hip/hip_runtime.h>
#include <math.h>

#define BATCH 32
#define CIN   256
#define LEN   8192
#define HL    (LEN/2)
#define ORD   8
#define NPOS  (BATCH*LEN)   // 262144 positions

struct Params { const float* p[32]; };

// Input index map (setup_inputs dict order):
// 0 x, 1 conv1_w, 2 conv1_b, 3 conv2_b
// per branch (w_=+0, c_=+14):
//   4 c1w, 5 c1b, 6 c2w, 7 c2b, 8 g1, 9 g2, 10 g3, 11 b1, 12 b2, 13 b3,
//   14 pxw, 15 pxb, 16 fcw, 17 fcb

// ws layout (floats):
// [0:32)   sum of pre-act, combo c = (br*2+conv)*8+ch
// [32:64)  sumsq of pre-act
// [64:80)  sum of c_pre (br*8+ch)
// [80:96)  sumsq of c_pre
// [96:608) per-sample sums of c: 96 + br*256 + b*8 + ch
// ---------------------------------------------------------------------------
// K1: x1[b,o,l] = sum_i x[b,i,l]*w[o,i] + bias[o]   (float2 per thread)
// ---------------------------------------------------------------------------
__global__ __launch_bounds__(256) void k1_pointwise(
    const float* __restrict__ x, const float* __restrict__ w,
    const float* __restrict__ bias, float* __restrict__ x1)
{
    __shared__ float wt[CIN][ORD];   // wt[i][o], rows 32B-aligned -> float4 reads
    int tid = threadIdx.x;
    for (int idx = tid; idx < CIN*ORD; idx += 256) {
        int o = idx >> 8, i = idx & 255;        // source layout [o][i]
        wt[i][o] = w[idx];
    }
    __syncthreads();

    int gid = blockIdx.x * 256 + tid;           // 512 blocks * 256 = 131072
    int b  = gid >> 12;                         // 4096 float2 per sample
    int l2 = gid & 4095;

    const float2* xrow = reinterpret_cast<const float2*>(x) + (size_t)b*CIN*HL + l2;
    float2 acc[ORD];
#pragma unroll
    for (int o = 0; o < ORD; o++) { acc[o].x = 0.f; acc[o].y = 0.f; }

#pragma unroll 8
    for (int i = 0; i < CIN; i++) {
        float2 xv = xrow[(size_t)i * HL];
        const float4* wr = reinterpret_cast<const float4*>(&wt[i][0]);
        float4 wa = wr[0], wb = wr[1];
        acc[0].x += xv.x*wa.x; acc[0].y += xv.y*wa.x;
        acc[1].x += xv.x*wa.y; acc[1].y += xv.y*wa.y;
        acc[2].x += xv.x*wa.z; acc[2].y += xv.y*wa.z;
        acc[3].x += xv.x*wa.w; acc[3].y += xv.y*wa.w;
        acc[4].x += xv.x*wb.x; acc[4].y += xv.y*wb.x;
        acc[5].x += xv.x*wb.y; acc[5].y += xv.y*wb.y;
        acc[6].x += xv.x*wb.z; acc[6].y += xv.y*wb.z;
        acc[7].x += xv.x*wb.w; acc[7].y += xv.y*wb.w;
    }

    float2* x1row = reinterpret_cast<float2*>(x1) + (size_t)b*ORD*HL + l2;
#pragma unroll
    for (int o = 0; o < ORD; o++) {
        float bo = bias[o];
        float2 r; r.x = acc[o].x + bo; r.y = acc[o].y + bo;
        x1row[(size_t)o * HL] = r;
    }
}

// ---------------------------------------------------------------------------
// shared helpers for the small conv branch (K2/K3/K4)
// ---------------------------------------------------------------------------
__device__ __forceinline__ void load_conv_lds(const Params& P, float* wl, float* bl, int tid)
{
    // wl[(bc*8+o)*24 + i*3 + k], bc = br*2+conv; conv weight arrays are [o][i][k]
    for (int idx = tid; idx < 4*192; idx += 256) {
        int which = idx / 192, s = idx - which*192;
        const float* src = (which==0) ? P.p[4] : (which==1) ? P.p[6]
                         : (which==2) ? P.p[18] : P.p[20];
        wl[idx] = src[s];
    }
    if (tid < 32) {
        int wq = tid >> 3, o = tid & 7;
        const float* bsrc = (wq==0) ? P.p[5] : (wq==1) ? P.p[7]
                          : (wq==2) ? P.p[19] : P.p[21];
        bl[tid] = bsrc[o];
    }
}

// pre-activations of both dilated convs for both branches at one (b,l)
__device__ __forceinline__ void compute_pre(
    const float* __restrict__ x1, int b, int l,
    const float* wl, const float* bl, float v[32])
{
    float xv[8][5];
    const float* xb = x1 + (size_t)b * ORD * LEN;
#pragma unroll
    for (int i = 0; i < 8; i++) {
#pragma unroll
        for (int d = 0; d < 5; d++) {
            int ld = l + d - 2;
            xv[i][d] = ((unsigned)ld < (unsigned)LEN) ? xb[(size_t)i*LEN + ld] : 0.f;
        }
    }
#pragma unroll
    for (int bc = 0; bc < 4; bc++) {
        int cv = bc & 1;                     // 0: dil=1 pad=1, 1: dil=2 pad=2
#pragma unroll
        for (int o = 0; o < 8; o++) {
            float a = bl[bc*8 + o];
            const float* wr = &wl[(bc*8 + o)*24];
#pragma unroll
            for (int i = 0; i < 8; i++) {
                if (cv == 0) {
                    a += wr[i*3+0]*xv[i][1] + wr[i*3+1]*xv[i][2] + wr[i*3+2]*xv[i][3];
                } else {
                    a += wr[i*3+0]*xv[i][0] + wr[i*3+1]*xv[i][2] + wr[i*3+2]*xv[i][4];
                }
            }
            v[bc*8 + o] = a;
        }
    }
}

// ---------------------------------------------------------------------------
// K2: global sum/sumsq of the 4 conv pre-activations (bn1/bn2 stats)
// ---------------------------------------------------------------------------
__global__ __launch_bounds__(256) void k2_stats(
    const float* __restrict__ x1, float* __restrict__ ws, Params P)
{
    __shared__ float wl[768], bl[32];
    __shared__ float part[256];
    int tid = threadIdx.x;
    load_conv_lds(P, wl, bl, tid);
    __syncthreads();

    int b = blockIdx.x >> 5;
    int l = ((blockIdx.x & 31) << 8) + tid;
    float v[32];
    compute_pre(x1, b, l, wl, bl, v);

    int lane = tid & 63, wv = tid >> 6;
#pragma unroll
    for (int c = 0; c < 32; c++) {
        float sv = v[c], sq = v[c]*v[c];
#pragma unroll
        for (int m = 32; m >= 1; m >>= 1) {
            sv += __shfl_xor(sv, m, 64);
            sq += __shfl_xor(sq, m, 64);
        }
        if (lane == 0) { part[c*4 + wv] = sv; part[(32+c)*4 + wv] = sq; }
    }
    __syncthreads();
    if (tid < 64) {
        float s = part[tid*4] + part[tid*4+1] + part[tid*4+2] + part[tid*4+3];
        atomicAdd(&ws[tid], s);
    }
}

// ---------------------------------------------------------------------------
// K3: apply bn1/bn2+relu, pointwise conv -> c_pre; accumulate bn3 stats
// ---------------------------------------------------------------------------
__global__ __launch_bounds__(256) void k3_cpre_stats(
    const float* __restrict__ x1, float* __restrict__ ws, Params P)
{
    __shared__ float wl[768], bl[32];
    __shared__ float pxl[128], pxbl[16];
    __shared__ float scl[32], shf[32];
    __shared__ float part[128];
    int tid = threadIdx.x;
    load_conv_lds(P, wl, bl, tid);
    if (tid < 128) pxl[tid]  = (tid < 64) ? P.p[14][tid] : P.p[28][tid-64];
    if (tid < 16)  pxbl[tid] = (tid < 8)  ? P.p[15][tid] : P.p[29][tid-8];
    if (tid < 32) {
        int br = tid >> 4, cv = (tid >> 3) & 1, o = tid & 7;
        const float Ninv = 1.0f / (float)NPOS;
        float m   = ws[tid]      * Ninv;
        float var = ws[32 + tid] * Ninv - m*m;
        const float* g  = P.p[ br ? (cv?23:22) : (cv?9:8)  ];
        const float* be = P.p[ br ? (cv?26:25) : (cv?12:11)];
        float sc = g[o] * rsqrtf(var + 1e-5f);
        scl[tid] = sc; shf[tid] = be[o] - m*sc;
    }
    __syncthreads();

    int b = blockIdx.x >> 5;
    int l = ((blockIdx.x & 31) << 8) + tid;
    float v[32];
    compute_pre(x1, b, l, wl, bl, v);

    float cp[16];
#pragma unroll
    for (int br = 0; br < 2; br++) {
        float s[8];
#pragma unroll
        for (int ch = 0; ch < 8; ch++) {
            int ca = (br*2+0)*8 + ch, cb = (br*2+1)*8 + ch;
            float aA = fmaxf(v[ca]*scl[ca] + shf[ca], 0.f);
            float aB = fmaxf(v[cb]*scl[cb] + shf[cb], 0.f);
            s[ch] = aA + aB;
        }
#pragma unroll
        for (int o = 0; o < 8; o++) {
            float a = pxbl[br*8 + o];
#pragma unroll
            for (int i = 0; i < 8; i++) a += pxl[br*64 + o*8 + i] * s[i];
            cp[br*8 + o] = a;
        }
    }
    int lane = tid & 63, wv = tid >> 6;
#pragma unroll
    for (int c = 0; c < 16; c++) {
        float sv = cp[c], sq = cp[c]*cp[c];
#pragma unroll
        for (int m = 32; m >= 1; m >>= 1) {
            sv += __shfl_xor(sv, m, 64);
            sq += __shfl_xor(sq, m, 64);
        }
        if (lane == 0) { part[c*4 + wv] = sv; part[(16+c)*4 + wv] = sq; }
    }
    __syncthreads();
    if (tid < 32) {
        float s = part[tid*4] + part[tid*4+1] + part[tid*4+2] + part[tid*4+3];
        atomicAdd(&ws[64 + tid], s);
    }
}

// ---------------------------------------------------------------------------
// K4: full recompute -> c = relu(bn3(c_pre)); per-sample channel sums
// ---------------------------------------------------------------------------
__global__ __launch_bounds__(256) void k4_csum(
    const float* __restrict__ x1, float* __restrict__ ws, Params P)
{
    __shared__ float wl[768], bl[32];
    __shared__ float pxl[128], pxbl[16];
    __shared__ float scl[32], shf[32];
    __shared__ float scl3[16], shf3[16];
    __shared__ float part[64];
    int tid = threadIdx.x;
    load_conv_lds(P, wl, bl, tid);
    if (tid < 128) pxl[tid]  = (tid < 64) ? P.p[14][tid] : P.p[28][tid-64];
    if (tid < 16)  pxbl[tid] = (tid < 8)  ? P.p[15][tid] : P.p[29][tid-8];
    const float Ninv = 1.0f / (float)NPOS;
    if (tid < 32) {
        int br = tid >> 4, cv = (tid >> 3) & 1, o = tid & 7;
        float m   = ws[tid]      * Ninv;
        float var = ws[32 + tid] * Ninv - m*m;
        const float* g  = P.p[ br ? (cv?23:22) : (cv?9:8)  ];
        const float* be = P.p[ br ? (cv?26:25) : (cv?12:11)];
        float sc = g[o] * rsqrtf(var + 1e-5f);
        scl[tid] = sc; shf[tid] = be[o] - m*sc;
    }
    if (tid < 16) {
        int br = tid >> 3, o = tid & 7;
        float m3 = ws[64 + tid] * Ninv;
        float v3 = ws[80 + tid] * Ninv - m3*m3;
        const float* g3 = P.p[ br ? 24 : 10 ];
        const float* b3 = P.p[ br ? 27 : 13 ];
        float sc = g3[o] * rsqrtf(v3 + 1e-5f);
        scl3[tid] = sc; shf3[tid] = b3[o] - m3*sc;
    }
    __syncthreads();

    int b = blockIdx.x >> 5;
    int l = ((blockIdx.x & 31) << 8) + tid;
    float v[32];
    compute_pre(x1, b, l, wl, bl, v);

    float cvl[16];
#pragma unroll
    for (int br = 0; br < 2; br++) {
        float s[8];
#pragma unroll
        for (int ch = 0; ch < 8; ch++) {
            int ca = (br*2+0)*8 + ch, cb = (br*2+1)*8 + ch;
            float aA = fmaxf(v[ca]*scl[ca] + shf[ca], 0.f);
            float aB = fmaxf(v[cb]*scl[cb] + shf[cb], 0.f);
            s[ch] = aA + aB;
        }
#pragma unroll
        for (int o = 0; o < 8; o++) {
            float a = pxbl[br*8 + o];
#pragma unroll
            for (int i = 0; i < 8; i++) a += pxl[br*64 + o*8 + i] * s[i];
            cvl[br*8 + o] = fmaxf(a*scl3[br*8+o] + shf3[br*8+o], 0.f);
        }
    }
    int lane = tid & 63, wv = tid >> 6;
#pragma unroll
    for (int c = 0; c < 16; c++) {
        float sv = cvl[c];
#pragma unroll
        for (int m = 32; m >= 1; m >>= 1) sv += __shfl_xor(sv, m, 64);
        if (lane == 0) part[c*4 + wv] = sv;
    }
    __syncthreads();
    if (tid < 16) {
        float s = part[tid*4] + part[tid*4+1] + part[tid*4+2] + part[tid*4+3];
        atomicAdd(&ws[96 + (tid >> 3)*256 + b*8 + (tid & 7)], s);
    }
}

// ---------------------------------------------------------------------------
// K6: fc -> width/center -> Hermite kernel (thread 0, LDS) -> 8x9 conv
// ---------------------------------------------------------------------------
__global__ __launch_bounds__(256) void k6_out(
    const float* __restrict__ x1, const float* __restrict__ ws, Params P,
    float* __restrict__ out)
{
    __shared__ float kern[8][9];
    __shared__ float xt[8][264];
    int tid = threadIdx.x;
    int b  = blockIdx.x >> 5;
    int t0 = (blockIdx.x & 31) << 8;

    for (int idx = tid; idx < 8*264; idx += 256) {
        int ch = idx / 264, pos = idx - ch*264;
        int l = t0 + pos - 4;
        xt[ch][pos] = ((unsigned)l < (unsigned)LEN)
                    ? x1[((size_t)b*ORD + ch)*LEN + l] : 0.f;
    }

    if (tid == 0) {
        const float Li = 1.0f / (float)LEN;
        float vw = P.p[17][0], vc = P.p[31][0];
#pragma unroll
        for (int ch = 0; ch < 8; ch++) {
            vw += P.p[16][ch] * (ws[96 +       b*8 + ch] * Li);
            vc += P.p[30][ch] * (ws[96 + 256 + b*8 + ch] * Li);
        }
        float width  = vw;
        float center = fminf(fmaxf(vc, 1.0f), 128.0f);

        float cst[7];
        cst[0] = 0.56418958354775628f;            // 1/sqrt(pi)
#pragma unroll
        for (int i = 1; i < 7; i++) cst[i] = cst[i-1] * sqrtf(2.0f / (float)i);

#pragma unroll
        for (int k = 0; k < 9; k++) {
            float t = width * ((float)k - center);
            float e = expf(-0.5f * t * t);
            float hp = 1.0f, hc = 2.0f * t;
            kern[0][k] = e * cst[0];
            kern[1][k] = e * cst[1] * hc;
#pragma unroll
            for (int i = 2; i < 7; i++) {
                float hn = 2.0f*t*hc - 2.0f*(float)(i-1)*hp;
                hp = hc; hc = hn;
                kern[i][k] = e * cst[i] * hc;
            }
            kern[7][k] = 1.0f / (1.0f + expf(-2.0f * t));
        }
#pragma unroll
        for (int i = 0; i < 7; i++) {
            float ss = 0.f;
#pragma unroll
            for (int k = 0; k < 9; k++) ss += kern[i][k]*kern[i][k];
            float inv = 1.0f / fmaxf(sqrtf(ss), 1e-12f);
#pragma unroll
            for (int k = 0; k < 9; k++) kern[i][k] *= inv;
        }
    }
    __syncthreads();

    float acc = P.p[3][0];
#pragma unroll
    for (int c = 0; c < 8; c++) {
#pragma unroll
        for (int j = 0; j < 9; j++) acc += xt[c][tid + j] * kern[c][j];
    }
    out[(size_t)b*LEN + t0 + tid] = acc;
}

// ---------------------------------------------------------------------------
extern "C" void kernel_launch(void* const* d_in, const int* in_sizes, int n_in,
                              void* d_out, int out_size, void* d_ws, size_t ws_size,
                              hipStream_t stream)
{
    (void)in_sizes; (void)n_in; (void)out_size; (void)ws_size;
    const float* x  = (const float*)d_in[0];
    const float* w1 = (const float*)d_in[1];
    const float* b1 = (const float*)d_in[2];
    float* outF = (float*)d_out;
    float* x1   = outF + (size_t)BATCH * LEN;   // second output region, reused
    float* ws   = (float*)d_ws;

    Params P;
    for (int i = 0; i < 32; i++) P.p[i] = (const float*)d_in[i];

    hipMemsetAsync(d_ws, 0, 4096, stream);
    k1_pointwise <<<512,  256, 0, stream>>>(x, w1, b1, x1);
    k2_stats     <<<1024, 256, 0, stream>>>(x1, ws, P);
    k3_cpre_stats<<<1024, 256, 0, stream>>>(x1, ws, P);
    k4_csum      <<<1024, 256, 0, stream>>>(x1, ws, P);
    k6_out       <<<1024, 256, 0, stream>>>(x1, ws, P, outF);
}

// Round 2
// 163.225 us; speedup vs baseline: 2.7698x; 2.7698x over previous
//
#include <hip/hip_runtime.h>
#include <math.h>

#define BATCH 32
#define CIN   256
#define LEN   8192
#define HL    (LEN/2)
#define ORD   8
#define NPOS  (BATCH*LEN)   // 262144 positions

struct Params { const float* p[32]; };

// Input index map (setup_inputs dict order):
// 0 x, 1 conv1_w, 2 conv1_b, 3 conv2_b
// w_ branch: 4 c1w, 5 c1b, 6 c2w, 7 c2b, 8 g1, 9 g2, 10 g3, 11 b1, 12 b2,
//            13 b3, 14 pxw, 15 pxb, 16 fcw, 17 fcb        (c_ branch = +14)

// ws layout (floats):
// [0:32)   sum of pre-act, combo c = (br*2+conv)*8+ch
// [32:64)  sumsq of pre-act
// [64:80)  sum of c_pre (br*8+ch)
// [80:96)  sumsq of c_pre
// [96:608) per-sample sums of c: 96 + br*256 + b*8 + ch

// ---------------------------------------------------------------------------
// K1: x1[b,o,l] = sum_i x[b,i,l]*w[o,i] + bias[o]   (float2 per thread)
// ---------------------------------------------------------------------------
__global__ __launch_bounds__(256) void k1_pointwise(
    const float* __restrict__ x, const float* __restrict__ w,
    const float* __restrict__ bias, float* __restrict__ x1)
{
    __shared__ float wt[CIN][ORD];   // wt[i][o]
    int tid = threadIdx.x;
    for (int idx = tid; idx < CIN*ORD; idx += 256) {
        int o = idx >> 8, i = idx & 255;        // source layout [o][i]
        wt[i][o] = w[idx];
    }
    __syncthreads();

    int gid = blockIdx.x * 256 + tid;           // 512 blocks * 256 = 131072
    int b  = gid >> 12;                         // 4096 float2 per sample
    int l2 = gid & 4095;

    const float2* xrow = reinterpret_cast<const float2*>(x) + (size_t)b*CIN*HL + l2;
    float2 acc[ORD];
#pragma unroll
    for (int o = 0; o < ORD; o++) { acc[o].x = 0.f; acc[o].y = 0.f; }

#pragma unroll 8
    for (int i = 0; i < CIN; i++) {
        float2 xv = xrow[(size_t)i * HL];
        const float4* wr = reinterpret_cast<const float4*>(&wt[i][0]);
        float4 wa = wr[0], wb = wr[1];
        acc[0].x += xv.x*wa.x; acc[0].y += xv.y*wa.x;
        acc[1].x += xv.x*wa.y; acc[1].y += xv.y*wa.y;
        acc[2].x += xv.x*wa.z; acc[2].y += xv.y*wa.z;
        acc[3].x += xv.x*wa.w; acc[3].y += xv.y*wa.w;
        acc[4].x += xv.x*wb.x; acc[4].y += xv.y*wb.x;
        acc[5].x += xv.x*wb.y; acc[5].y += xv.y*wb.y;
        acc[6].x += xv.x*wb.z; acc[6].y += xv.y*wb.z;
        acc[7].x += xv.x*wb.w; acc[7].y += xv.y*wb.w;
    }

    float2* x1row = reinterpret_cast<float2*>(x1) + (size_t)b*ORD*HL + l2;
#pragma unroll
    for (int o = 0; o < ORD; o++) {
        float bo = bias[o];
        float2 r; r.x = acc[o].x + bo; r.y = acc[o].y + bo;
        x1row[(size_t)o * HL] = r;
    }
}

// ---------------------------------------------------------------------------
// shared helpers for the small conv branch (K2/K3/K4)
// ---------------------------------------------------------------------------
__device__ __forceinline__ void load_conv_lds(const Params& P, float* wl, float* bl, int tid)
{
    // wl[(bc*8+o)*24 + i*3 + k], bc = br*2+conv; conv weight arrays are [o][i][k]
    for (int idx = tid; idx < 4*192; idx += 256) {
        int which = idx / 192, s = idx - which*192;
        const float* src = (which==0) ? P.p[4] : (which==1) ? P.p[6]
                         : (which==2) ? P.p[18] : P.p[20];
        wl[idx] = src[s];
    }
    if (tid < 32) {
        int wq = tid >> 3, o = tid & 7;
        const float* bsrc = (wq==0) ? P.p[5] : (wq==1) ? P.p[7]
                          : (wq==2) ? P.p[19] : P.p[21];
        bl[tid] = bsrc[o];
    }
}

#define XT_W 268
// stage x1[b, :, t0-2 .. t0+257] into xt[8][XT_W], interior at offset 4
__device__ __forceinline__ void stage_tile_h2(
    const float* __restrict__ x1, int b, int t0, float (*xt)[XT_W], int tid)
{
    int ch = tid >> 5, q = tid & 31;
    const float* src = x1 + ((size_t)b*ORD + ch)*LEN + t0;
    float4 a0 = *reinterpret_cast<const float4*>(src + q*8);
    float4 a1 = *reinterpret_cast<const float4*>(src + q*8 + 4);
    *reinterpret_cast<float4*>(&xt[ch][4 + q*8]) = a0;
    *reinterpret_cast<float4*>(&xt[ch][8 + q*8]) = a1;
    if (q < 2) {                       // left halo: l = t0-2+q -> xt[2+q]
        int l = t0 - 2 + q;
        xt[ch][2 + q] = (l >= 0) ? src[q - 2] : 0.f;
    } else if (q < 4) {                // right halo: l = t0+256+(q-2) -> xt[258+q]
        int l = t0 + 256 + (q - 2);
        xt[ch][258 + q] = (l < LEN) ? src[256 + q - 2] : 0.f;
    }
}

// load the 5-wide window for this thread's position from the LDS tile
#define LOAD_XV(xt, tid, xv)                                  \
    _Pragma("unroll")                                         \
    for (int i_ = 0; i_ < 8; i_++) {                          \
        _Pragma("unroll")                                     \
        for (int d_ = 0; d_ < 5; d_++)                        \
            xv[i_][d_] = xt[i_][2 + (tid) + d_];              \
    }

// one conv pre-activation: combo bc (0..3), out channel o
__device__ __forceinline__ float conv_pre(
    const float xv[8][5], const float* wl, const float* bl, int bc, int o)
{
    float a = bl[bc*8 + o];
    const float* wr = &wl[(bc*8 + o)*24];
    if ((bc & 1) == 0) {               // dilation 1, pad 1
#pragma unroll
        for (int i = 0; i < 8; i++)
            a += wr[i*3+0]*xv[i][1] + wr[i*3+1]*xv[i][2] + wr[i*3+2]*xv[i][3];
    } else {                           // dilation 2, pad 2
#pragma unroll
        for (int i = 0; i < 8; i++)
            a += wr[i*3+0]*xv[i][0] + wr[i*3+1]*xv[i][2] + wr[i*3+2]*xv[i][4];
    }
    return a;
}

__device__ __forceinline__ void wave_reduce2(float& sv, float& sq)
{
#pragma unroll
    for (int m = 32; m >= 1; m >>= 1) {
        sv += __shfl_xor(sv, m, 64);
        sq += __shfl_xor(sq, m, 64);
    }
}
__device__ __forceinline__ void wave_reduce1(float& sv)
{
#pragma unroll
    for (int m = 32; m >= 1; m >>= 1) sv += __shfl_xor(sv, m, 64);
}

// ---------------------------------------------------------------------------
// K2: global sum/sumsq of the 4 conv pre-activations (bn1/bn2 stats)
// ---------------------------------------------------------------------------
__global__ __launch_bounds__(256, 2) void k2_stats(
    const float* __restrict__ x1, float* __restrict__ ws, Params P)
{
    __shared__ float wl[768], bl[32];
    __shared__ float xt[8][XT_W];
    __shared__ float part[256];
    int tid = threadIdx.x;
    load_conv_lds(P, wl, bl, tid);
    int b  = blockIdx.x >> 5;
    int t0 = (blockIdx.x & 31) << 8;
    stage_tile_h2(x1, b, t0, xt, tid);
    __syncthreads();

    float xv[8][5];
    LOAD_XV(xt, tid, xv);

    int lane = tid & 63, wv = tid >> 6;
#pragma unroll
    for (int bc = 0; bc < 4; bc++) {
#pragma unroll
        for (int o = 0; o < 8; o++) {
            float a  = conv_pre(xv, wl, bl, bc, o);
            float sv = a, sq = a*a;
            wave_reduce2(sv, sq);
            if (lane == 0) {
                int c = bc*8 + o;
                part[c*4 + wv] = sv; part[(32+c)*4 + wv] = sq;
            }
        }
    }
    __syncthreads();
    if (tid < 64) {
        float s = part[tid*4] + part[tid*4+1] + part[tid*4+2] + part[tid*4+3];
        atomicAdd(&ws[tid], s);
    }
}

// ---------------------------------------------------------------------------
// K3: apply bn1/bn2+relu, pointwise conv -> c_pre; accumulate bn3 stats
// ---------------------------------------------------------------------------
__global__ __launch_bounds__(256, 2) void k3_cpre_stats(
    const float* __restrict__ x1, float* __restrict__ ws, Params P)
{
    __shared__ float wl[768], bl[32];
    __shared__ float pxl[128], pxbl[16];
    __shared__ float scl[32], shf[32];
    __shared__ float xt[8][XT_W];
    __shared__ float part[128];
    int tid = threadIdx.x;
    load_conv_lds(P, wl, bl, tid);
    if (tid < 128) pxl[tid]  = (tid < 64) ? P.p[14][tid] : P.p[28][tid-64];
    if (tid < 16)  pxbl[tid] = (tid < 8)  ? P.p[15][tid] : P.p[29][tid-8];
    if (tid >= 128 && tid < 160) {
        int c = tid - 128;
        int br = c >> 4, cv = (c >> 3) & 1, o = c & 7;
        const float Ninv = 1.0f / (float)NPOS;
        float m   = ws[c]      * Ninv;
        float var = ws[32 + c] * Ninv - m*m;
        const float* g  = P.p[ br ? (cv?23:22) : (cv?9:8)  ];
        const float* be = P.p[ br ? (cv?26:25) : (cv?12:11)];
        float sc = g[o] * rsqrtf(var + 1e-5f);
        scl[c] = sc; shf[c] = be[o] - m*sc;
    }
    int b  = blockIdx.x >> 5;
    int t0 = (blockIdx.x & 31) << 8;
    stage_tile_h2(x1, b, t0, xt, tid);
    __syncthreads();

    float xv[8][5];
    LOAD_XV(xt, tid, xv);

    int lane = tid & 63, wv = tid >> 6;
#pragma unroll
    for (int br = 0; br < 2; br++) {
        float s[8];
#pragma unroll
        for (int ch = 0; ch < 8; ch++) {
            int ca = (br*2+0)*8 + ch, cb = (br*2+1)*8 + ch;
            float aA = fmaxf(conv_pre(xv, wl, bl, br*2+0, ch)*scl[ca] + shf[ca], 0.f);
            float aB = fmaxf(conv_pre(xv, wl, bl, br*2+1, ch)*scl[cb] + shf[cb], 0.f);
            s[ch] = aA + aB;
        }
#pragma unroll
        for (int o = 0; o < 8; o++) {
            float a = pxbl[br*8 + o];
#pragma unroll
            for (int i = 0; i < 8; i++) a += pxl[br*64 + o*8 + i] * s[i];
            float sv = a, sq = a*a;
            wave_reduce2(sv, sq);
            if (lane == 0) {
                int c = br*8 + o;
                part[c*4 + wv] = sv; part[(16+c)*4 + wv] = sq;
            }
        }
    }
    __syncthreads();
    if (tid < 32) {
        float s = part[tid*4] + part[tid*4+1] + part[tid*4+2] + part[tid*4+3];
        atomicAdd(&ws[64 + tid], s);
    }
}

// ---------------------------------------------------------------------------
// K4: full recompute -> c = relu(bn3(c_pre)); per-sample channel sums
// ---------------------------------------------------------------------------
__global__ __launch_bounds__(256, 2) void k4_csum(
    const float* __restrict__ x1, float* __restrict__ ws, Params P)
{
    __shared__ float wl[768], bl[32];
    __shared__ float pxl[128], pxbl[16];
    __shared__ float scl[32], shf[32];
    __shared__ float scl3[16], shf3[16];
    __shared__ float xt[8][XT_W];
    __shared__ float part[64];
    int tid = threadIdx.x;
    load_conv_lds(P, wl, bl, tid);
    if (tid < 128) pxl[tid]  = (tid < 64) ? P.p[14][tid] : P.p[28][tid-64];
    if (tid < 16)  pxbl[tid] = (tid < 8)  ? P.p[15][tid] : P.p[29][tid-8];
    const float Ninv = 1.0f / (float)NPOS;
    if (tid >= 128 && tid < 160) {
        int c = tid - 128;
        int br = c >> 4, cv = (c >> 3) & 1, o = c & 7;
        float m   = ws[c]      * Ninv;
        float var = ws[32 + c] * Ninv - m*m;
        const float* g  = P.p[ br ? (cv?23:22) : (cv?9:8)  ];
        const float* be = P.p[ br ? (cv?26:25) : (cv?12:11)];
        float sc = g[o] * rsqrtf(var + 1e-5f);
        scl[c] = sc; shf[c] = be[o] - m*sc;
    }
    if (tid >= 160 && tid < 176) {
        int c = tid - 160;
        int br = c >> 3, o = c & 7;
        float m3 = ws[64 + c] * Ninv;
        float v3 = ws[80 + c] * Ninv - m3*m3;
        const float* g3 = P.p[ br ? 24 : 10 ];
        const float* b3 = P.p[ br ? 27 : 13 ];
        float sc = g3[o] * rsqrtf(v3 + 1e-5f);
        scl3[c] = sc; shf3[c] = b3[o] - m3*sc;
    }
    int b  = blockIdx.x >> 5;
    int t0 = (blockIdx.x & 31) << 8;
    stage_tile_h2(x1, b, t0, xt, tid);
    __syncthreads();

    float xv[8][5];
    LOAD_XV(xt, tid, xv);

    int lane = tid & 63, wv = tid >> 6;
#pragma unroll
    for (int br = 0; br < 2; br++) {
        float s[8];
#pragma unroll
        for (int ch = 0; ch < 8; ch++) {
            int ca = (br*2+0)*8 + ch, cb = (br*2+1)*8 + ch;
            float aA = fmaxf(conv_pre(xv, wl, bl, br*2+0, ch)*scl[ca] + shf[ca], 0.f);
            float aB = fmaxf(conv_pre(xv, wl, bl, br*2+1, ch)*scl[cb] + shf[cb], 0.f);
            s[ch] = aA + aB;
        }
#pragma unroll
        for (int o = 0; o < 8; o++) {
            float a = pxbl[br*8 + o];
#pragma unroll
            for (int i = 0; i < 8; i++) a += pxl[br*64 + o*8 + i] * s[i];
            int c = br*8 + o;
            float sv = fmaxf(a*scl3[c] + shf3[c], 0.f);
            wave_reduce1(sv);
            if (lane == 0) part[c*4 + wv] = sv;
        }
    }
    __syncthreads();
    if (tid < 16) {
        float s = part[tid*4] + part[tid*4+1] + part[tid*4+2] + part[tid*4+3];
        atomicAdd(&ws[96 + (tid >> 3)*256 + b*8 + (tid & 7)], s);
    }
}

// ---------------------------------------------------------------------------
// K6: fc -> width/center -> Hermite kernel (parallel over k) -> 8x9 conv
// ---------------------------------------------------------------------------
#define XT6_W 272
__global__ __launch_bounds__(256) void k6_out(
    const float* __restrict__ x1, const float* __restrict__ ws, Params P,
    float* __restrict__ out)
{
    __shared__ float kern[8][9];
    __shared__ float xt[8][XT6_W];
    int tid = threadIdx.x;
    int b  = blockIdx.x >> 5;
    int t0 = (blockIdx.x & 31) << 8;

    {   // vectorized stage: interior at offset 8, halo 4 each side
        int ch = tid >> 5, q = tid & 31;
        const float* src = x1 + ((size_t)b*ORD + ch)*LEN + t0;
        float4 a0 = *reinterpret_cast<const float4*>(src + q*8);
        float4 a1 = *reinterpret_cast<const float4*>(src + q*8 + 4);
        *reinterpret_cast<float4*>(&xt[ch][8  + q*8]) = a0;
        *reinterpret_cast<float4*>(&xt[ch][12 + q*8]) = a1;
        if (q < 4) {                   // left: l = t0-4+q -> xt[4+q]
            int l = t0 - 4 + q;
            xt[ch][4 + q] = (l >= 0) ? src[q - 4] : 0.f;
        } else if (q < 8) {            // right: l = t0+256+(q-4) -> xt[260+q]
            int l = t0 + 256 + (q - 4);
            xt[ch][260 + q] = (l < LEN) ? src[256 + q - 4] : 0.f;
        }
    }

    if (tid < 9) {
        // each of 9 threads: fc (redundant) + its own k column
        const float Li = 1.0f / (float)LEN;
        float vw = P.p[17][0], vc = P.p[31][0];
#pragma unroll
        for (int ch = 0; ch < 8; ch++) {
            vw += P.p[16][ch] * (ws[96 +       b*8 + ch] * Li);
            vc += P.p[30][ch] * (ws[96 + 256 + b*8 + ch] * Li);
        }
        float width  = vw;
        float center = fminf(fmaxf(vc, 1.0f), 128.0f);

        float cst[7];
        cst[0] = 0.56418958354775628f;            // 1/sqrt(pi)
#pragma unroll
        for (int i = 1; i < 7; i++) cst[i] = cst[i-1] * sqrtf(2.0f / (float)i);

        int k = tid;
        float t = width * ((float)k - center);
        float e = expf(-0.5f * t * t);
        float hp = 1.0f, hc = 2.0f * t;
        kern[0][k] = e * cst[0];
        kern[1][k] = e * cst[1] * hc;
#pragma unroll
        for (int i = 2; i < 7; i++) {
            float hn = 2.0f*t*hc - 2.0f*(float)(i-1)*hp;
            hp = hc; hc = hn;
            kern[i][k] = e * cst[i] * hc;
        }
        kern[7][k] = 1.0f / (1.0f + expf(-2.0f * t));
    }
    __syncthreads();
    if (tid < 7) {                     // normalize rows 0..6 over k
        float ss = 0.f;
#pragma unroll
        for (int k = 0; k < 9; k++) ss += kern[tid][k]*kern[tid][k];
        float inv = 1.0f / fmaxf(sqrtf(ss), 1e-12f);
#pragma unroll
        for (int k = 0; k < 9; k++) kern[tid][k] *= inv;
    }
    __syncthreads();

    float acc = P.p[3][0];
#pragma unroll
    for (int c = 0; c < 8; c++) {
#pragma unroll
        for (int j = 0; j < 9; j++) acc += xt[c][4 + tid + j] * kern[c][j];
    }
    out[(size_t)b*LEN + t0 + tid] = acc;
}

// ---------------------------------------------------------------------------
extern "C" void kernel_launch(void* const* d_in, const int* in_sizes, int n_in,
                              void* d_out, int out_size, void* d_ws, size_t ws_size,
                              hipStream_t stream)
{
    (void)in_sizes; (void)n_in; (void)out_size; (void)ws_size;
    const float* x  = (const float*)d_in[0];
    const float* w1 = (const float*)d_in[1];
    const float* b1 = (const float*)d_in[2];
    float* outF = (float*)d_out;
    float* x1   = outF + (size_t)BATCH * LEN;   // second output region, reused
    float* ws   = (float*)d_ws;

    Params P;
    for (int i = 0; i < 32; i++) P.p[i] = (const float*)d_in[i];

    hipMemsetAsync(d_ws, 0, 4096, stream);
    k1_pointwise <<<512,  256, 0, stream>>>(x, w1, b1, x1);
    k2_stats     <<<1024, 256, 0, stream>>>(x1, ws, P);
    k3_cpre_stats<<<1024, 256, 0, stream>>>(x1, ws, P);
    k4_csum      <<<1024, 256, 0, stream>>>(x1, ws, P);
    k6_out       <<<1024, 256, 0, stream>>>(x1, ws, P, outF);
}

// Round 3
// 142.613 us; speedup vs baseline: 3.1701x; 1.1445x over previous
//
#include <hip/hip_runtime.h>
#include <math.h>

#define BATCH 32
#define CIN   256
#define LEN   8192
#define HL    (LEN/2)
#define ORD   8
#define NPOS  (BATCH*LEN)   // 262144 positions

struct Params { const float* p[32]; };

// Input index map (setup_inputs dict order):
// 0 x, 1 conv1_w, 2 conv1_b, 3 conv2_b
// w_ branch: 4 c1w, 5 c1b, 6 c2w, 7 c2b, 8 g1, 9 g2, 10 g3, 11 b1, 12 b2,
//            13 b3, 14 pxw, 15 pxb, 16 fcw, 17 fcb        (c_ branch = +14)

// ws layout (floats):
// [0:32)   sum of conv pre-act, combo c = (br*2+conv)*8+ch
// [32:64)  sumsq of conv pre-act
// [64:80)  sum of c_pre (br*8+ch)
// [80:96)  sumsq of c_pre
// [96:608) per-sample sums of c: 96 + br*256 + b*8 + ch

// ---------------------------------------------------------------------------
// shared helpers
// ---------------------------------------------------------------------------
__device__ __forceinline__ void load_conv_lds(const Params& P, float* wl, float* bl, int tid)
{
    // wl[(bc*8+o)*24 + i*3 + k], bc = br*2+conv; conv weight arrays are [o][i][k]
    for (int idx = tid; idx < 4*192; idx += 256) {
        int which = idx / 192, s = idx - which*192;
        const float* src = (which==0) ? P.p[4] : (which==1) ? P.p[6]
                         : (which==2) ? P.p[18] : P.p[20];
        wl[idx] = src[s];
    }
    if (tid < 32) {
        int wq = tid >> 3, o = tid & 7;
        const float* bsrc = (wq==0) ? P.p[5] : (wq==1) ? P.p[7]
                          : (wq==2) ? P.p[19] : P.p[21];
        bl[tid] = bsrc[o];
    }
}

// conv pre-activation from a 6-wide window; s = 0/1 selects position p0/p0+1
__device__ __forceinline__ float conv6(
    const float xv[8][6], const float* wl, const float* bl, int bc, int o, int s)
{
    float a = bl[bc*8 + o];
    const float* wr = &wl[(bc*8 + o)*24];
    if ((bc & 1) == 0) {               // dilation 1, pad 1
#pragma unroll
        for (int i = 0; i < 8; i++)
            a += wr[i*3+0]*xv[i][s+1] + wr[i*3+1]*xv[i][s+2] + wr[i*3+2]*xv[i][s+3];
    } else {                           // dilation 2, pad 2
#pragma unroll
        for (int i = 0; i < 8; i++)
            a += wr[i*3+0]*xv[i][s+0] + wr[i*3+1]*xv[i][s+2] + wr[i*3+2]*xv[i][s+4];
    }
    return a;
}

__device__ __forceinline__ void wave_reduce2(float& sv, float& sq)
{
#pragma unroll
    for (int m = 32; m >= 1; m >>= 1) {
        sv += __shfl_xor(sv, m, 64);
        sq += __shfl_xor(sq, m, 64);
    }
}
__device__ __forceinline__ void wave_reduce1(float& sv)
{
#pragma unroll
    for (int m = 32; m >= 1; m >>= 1) sv += __shfl_xor(sv, m, 64);
}

#define XT_W 520   // 4 (align/halo) + 512 interior + 4
// window load: position pair (2*tid, 2*tid+1) needs xt[ch][2+2*tid .. 2+2*tid+5]
#define LOAD_XV6(xt, tid, xv)                                 \
    _Pragma("unroll")                                         \
    for (int i_ = 0; i_ < 8; i_++) {                          \
        _Pragma("unroll")                                     \
        for (int d_ = 0; d_ < 6; d_++)                        \
            xv[i_][d_] = xt[i_][2 + 2*(tid) + d_];            \
    }

// stage x1 tile [t0-2, t0+514) for 8 channels from global into xt
__device__ __forceinline__ void stage_tile(
    const float* __restrict__ x1, int b, int t0, float (*xt)[XT_W], int tid)
{
    int ch = tid >> 5, q = tid & 31;
    const float* src = x1 + ((size_t)b*ORD + ch)*LEN + t0 + q*16;
    float4* dst = reinterpret_cast<float4*>(&xt[ch][4 + q*16]);
#pragma unroll
    for (int j = 0; j < 4; j++) dst[j] = reinterpret_cast<const float4*>(src)[j];
    if (tid < 32) {
        int hc = tid >> 2, hh = tid & 3;
        int l   = t0 + ((hh < 2) ? (hh - 2) : (510 + hh));   // -2,-1,512,513
        int idx = (hh < 2) ? (2 + hh) : (514 + hh);          // 2,3,516,517
        xt[hc][idx] = ((unsigned)l < (unsigned)LEN)
                    ? x1[((size_t)b*ORD + hc)*LEN + l] : 0.f;
    }
}

// ---------------------------------------------------------------------------
// K1: pointwise GEMM -> x1 (global + LDS tile) -> bn1/bn2 stats (fused)
// ---------------------------------------------------------------------------
__global__ __launch_bounds__(256, 2) void k1_gemm_stats(
    const float* __restrict__ x, const float* __restrict__ w,
    const float* __restrict__ bias, float* __restrict__ x1,
    float* __restrict__ ws, Params P)
{
    __shared__ float wt[CIN][ORD];   // wt[i][o]
    __shared__ float wl[768], bl[32];
    __shared__ float xt[8][XT_W];
    __shared__ float part[256];
    int tid = threadIdx.x;
    for (int idx = tid; idx < CIN*ORD; idx += 256) {
        int o = idx >> 8, i = idx & 255;        // source layout [o][i]
        wt[i][o] = w[idx];
    }
    load_conv_lds(P, wl, bl, tid);
    __syncthreads();                            // wt ready (main loop + halo)

    int b  = blockIdx.x >> 4;                   // 16 blocks per sample
    int t0 = (blockIdx.x & 15) << 9;            // 512 positions per block

    const float2* xrow = reinterpret_cast<const float2*>(x)
                       + (size_t)b*CIN*HL + (t0 >> 1) + tid;
    float2 acc[ORD];
#pragma unroll
    for (int o = 0; o < ORD; o++) { acc[o].x = 0.f; acc[o].y = 0.f; }

#pragma unroll 8
    for (int i = 0; i < CIN; i++) {
        float2 xv2 = xrow[(size_t)i * HL];
        const float4* wr = reinterpret_cast<const float4*>(&wt[i][0]);
        float4 wa = wr[0], wb = wr[1];
        acc[0].x += xv2.x*wa.x; acc[0].y += xv2.y*wa.x;
        acc[1].x += xv2.x*wa.y; acc[1].y += xv2.y*wa.y;
        acc[2].x += xv2.x*wa.z; acc[2].y += xv2.y*wa.z;
        acc[3].x += xv2.x*wa.w; acc[3].y += xv2.y*wa.w;
        acc[4].x += xv2.x*wb.x; acc[4].y += xv2.y*wb.x;
        acc[5].x += xv2.x*wb.y; acc[5].y += xv2.y*wb.y;
        acc[6].x += xv2.x*wb.z; acc[6].y += xv2.y*wb.z;
        acc[7].x += xv2.x*wb.w; acc[7].y += xv2.y*wb.w;
    }

    float2* x1row = reinterpret_cast<float2*>(x1)
                  + (size_t)b*ORD*HL + (t0 >> 1) + tid;
#pragma unroll
    for (int o = 0; o < ORD; o++) {
        float bo = bias[o];
        float2 r; r.x = acc[o].x + bo; r.y = acc[o].y + bo;
        x1row[(size_t)o * HL] = r;
        *reinterpret_cast<float2*>(&xt[o][4 + 2*tid]) = r;
    }

    // halo positions t0-2, t0-1, t0+512, t0+513 (x8 ch), recomputed from x
    if (tid < 32) {
        int hp = tid >> 3, ch = tid & 7;
        int l  = t0 + ((hp < 2) ? (hp - 2) : (510 + hp));
        float a = 0.f;
        if ((unsigned)l < (unsigned)LEN) {
            const float* xp = x + (size_t)b*CIN*LEN + l;
#pragma unroll 4
            for (int i = 0; i < CIN; i++) a += xp[(size_t)i*LEN] * wt[i][ch];
            a += bias[ch];
        }
        int idx = (hp < 2) ? (2 + hp) : (514 + hp);
        xt[ch][idx] = a;
    }
    __syncthreads();

    float xv[8][6];
    LOAD_XV6(xt, tid, xv);

    int lane = tid & 63, wv = tid >> 6;
#pragma unroll
    for (int bc = 0; bc < 4; bc++) {
#pragma unroll
        for (int o = 0; o < 8; o++) {
            float a0 = conv6(xv, wl, bl, bc, o, 0);
            float a1 = conv6(xv, wl, bl, bc, o, 1);
            float sv = a0 + a1, sq = a0*a0 + a1*a1;
            wave_reduce2(sv, sq);
            if (lane == 0) {
                int c = bc*8 + o;
                part[c*4 + wv] = sv; part[(32+c)*4 + wv] = sq;
            }
        }
    }
    __syncthreads();
    if (tid < 64) {
        float s = part[tid*4] + part[tid*4+1] + part[tid*4+2] + part[tid*4+3];
        atomicAdd(&ws[tid], s);
    }
}

// ---------------------------------------------------------------------------
// K3: apply bn1/bn2+relu, pointwise conv -> c_pre; accumulate bn3 stats
// ---------------------------------------------------------------------------
__global__ __launch_bounds__(256, 2) void k3_cpre_stats(
    const float* __restrict__ x1, float* __restrict__ ws, Params P)
{
    __shared__ float wl[768], bl[32];
    __shared__ float pxl[128], pxbl[16];
    __shared__ float scl[32], shf[32];
    __shared__ float xt[8][XT_W];
    __shared__ float part[128];
    int tid = threadIdx.x;
    load_conv_lds(P, wl, bl, tid);
    if (tid < 128) pxl[tid]  = (tid < 64) ? P.p[14][tid] : P.p[28][tid-64];
    if (tid < 16)  pxbl[tid] = (tid < 8)  ? P.p[15][tid] : P.p[29][tid-8];
    if (tid >= 128 && tid < 160) {
        int c = tid - 128;
        int br = c >> 4, cv = (c >> 3) & 1, o = c & 7;
        const float Ninv = 1.0f / (float)NPOS;
        float m   = ws[c]      * Ninv;
        float var = ws[32 + c] * Ninv - m*m;
        const float* g  = P.p[ br ? (cv?23:22) : (cv?9:8)  ];
        const float* be = P.p[ br ? (cv?26:25) : (cv?12:11)];
        float sc = g[o] * rsqrtf(var + 1e-5f);
        scl[c] = sc; shf[c] = be[o] - m*sc;
    }
    int b  = blockIdx.x >> 4;
    int t0 = (blockIdx.x & 15) << 9;
    stage_tile(x1, b, t0, xt, tid);
    __syncthreads();

    float xv[8][6];
    LOAD_XV6(xt, tid, xv);

    int lane = tid & 63, wv = tid >> 6;
#pragma unroll
    for (int br = 0; br < 2; br++) {
        float s0[8], s1[8];
#pragma unroll
        for (int ch = 0; ch < 8; ch++) {
            int ca = (br*2+0)*8 + ch, cb = (br*2+1)*8 + ch;
            s0[ch] = fmaxf(conv6(xv,wl,bl,br*2+0,ch,0)*scl[ca] + shf[ca], 0.f)
                   + fmaxf(conv6(xv,wl,bl,br*2+1,ch,0)*scl[cb] + shf[cb], 0.f);
            s1[ch] = fmaxf(conv6(xv,wl,bl,br*2+0,ch,1)*scl[ca] + shf[ca], 0.f)
                   + fmaxf(conv6(xv,wl,bl,br*2+1,ch,1)*scl[cb] + shf[cb], 0.f);
        }
#pragma unroll
        for (int o = 0; o < 8; o++) {
            float a0 = pxbl[br*8 + o], a1 = a0;
#pragma unroll
            for (int i = 0; i < 8; i++) {
                a0 += pxl[br*64 + o*8 + i] * s0[i];
                a1 += pxl[br*64 + o*8 + i] * s1[i];
            }
            float sv = a0 + a1, sq = a0*a0 + a1*a1;
            wave_reduce2(sv, sq);
            if (lane == 0) {
                int c = br*8 + o;
                part[c*4 + wv] = sv; part[(16+c)*4 + wv] = sq;
            }
        }
    }
    __syncthreads();
    if (tid < 32) {
        float s = part[tid*4] + part[tid*4+1] + part[tid*4+2] + part[tid*4+3];
        atomicAdd(&ws[64 + tid], s);
    }
}

// ---------------------------------------------------------------------------
// K4: full recompute -> c = relu(bn3(c_pre)); per-sample channel sums
// ---------------------------------------------------------------------------
__global__ __launch_bounds__(256, 2) void k4_csum(
    const float* __restrict__ x1, float* __restrict__ ws, Params P)
{
    __shared__ float wl[768], bl[32];
    __shared__ float pxl[128], pxbl[16];
    __shared__ float scl[32], shf[32];
    __shared__ float scl3[16], shf3[16];
    __shared__ float xt[8][XT_W];
    __shared__ float part[64];
    int tid = threadIdx.x;
    load_conv_lds(P, wl, bl, tid);
    if (tid < 128) pxl[tid]  = (tid < 64) ? P.p[14][tid] : P.p[28][tid-64];
    if (tid < 16)  pxbl[tid] = (tid < 8)  ? P.p[15][tid] : P.p[29][tid-8];
    const float Ninv = 1.0f / (float)NPOS;
    if (tid >= 128 && tid < 160) {
        int c = tid - 128;
        int br = c >> 4, cv = (c >> 3) & 1, o = c & 7;
        float m   = ws[c]      * Ninv;
        float var = ws[32 + c] * Ninv - m*m;
        const float* g  = P.p[ br ? (cv?23:22) : (cv?9:8)  ];
        const float* be = P.p[ br ? (cv?26:25) : (cv?12:11)];
        float sc = g[o] * rsqrtf(var + 1e-5f);
        scl[c] = sc; shf[c] = be[o] - m*sc;
    }
    if (tid >= 160 && tid < 176) {
        int c = tid - 160;
        int br = c >> 3, o = c & 7;
        float m3 = ws[64 + c] * Ninv;
        float v3 = ws[80 + c] * Ninv - m3*m3;
        const float* g3 = P.p[ br ? 24 : 10 ];
        const float* b3 = P.p[ br ? 27 : 13 ];
        float sc = g3[o] * rsqrtf(v3 + 1e-5f);
        scl3[c] = sc; shf3[c] = b3[o] - m3*sc;
    }
    int b  = blockIdx.x >> 4;
    int t0 = (blockIdx.x & 15) << 9;
    stage_tile(x1, b, t0, xt, tid);
    __syncthreads();

    float xv[8][6];
    LOAD_XV6(xt, tid, xv);

    int lane = tid & 63, wv = tid >> 6;
#pragma unroll
    for (int br = 0; br < 2; br++) {
        float s0[8], s1[8];
#pragma unroll
        for (int ch = 0; ch < 8; ch++) {
            int ca = (br*2+0)*8 + ch, cb = (br*2+1)*8 + ch;
            s0[ch] = fmaxf(conv6(xv,wl,bl,br*2+0,ch,0)*scl[ca] + shf[ca], 0.f)
                   + fmaxf(conv6(xv,wl,bl,br*2+1,ch,0)*scl[cb] + shf[cb], 0.f);
            s1[ch] = fmaxf(conv6(xv,wl,bl,br*2+0,ch,1)*scl[ca] + shf[ca], 0.f)
                   + fmaxf(conv6(xv,wl,bl,br*2+1,ch,1)*scl[cb] + shf[cb], 0.f);
        }
#pragma unroll
        for (int o = 0; o < 8; o++) {
            float a0 = pxbl[br*8 + o], a1 = a0;
#pragma unroll
            for (int i = 0; i < 8; i++) {
                a0 += pxl[br*64 + o*8 + i] * s0[i];
                a1 += pxl[br*64 + o*8 + i] * s1[i];
            }
            int c = br*8 + o;
            float v0 = fmaxf(a0*scl3[c] + shf3[c], 0.f);
            float v1 = fmaxf(a1*scl3[c] + shf3[c], 0.f);
            float sv = v0 + v1;
            wave_reduce1(sv);
            if (lane == 0) part[c*4 + wv] = sv;
        }
    }
    __syncthreads();
    if (tid < 16) {
        float s = part[tid*4] + part[tid*4+1] + part[tid*4+2] + part[tid*4+3];
        atomicAdd(&ws[96 + (tid >> 3)*256 + b*8 + (tid & 7)], s);
    }
}

// ---------------------------------------------------------------------------
// K6: fc -> width/center -> Hermite kernel (parallel over k) -> 8x9 conv
// ---------------------------------------------------------------------------
#define XT6_W 272
__global__ __launch_bounds__(256) void k6_out(
    const float* __restrict__ x1, const float* __restrict__ ws, Params P,
    float* __restrict__ out)
{
    __shared__ float kern[8][9];
    __shared__ float xt[8][XT6_W];
    int tid = threadIdx.x;
    int b  = blockIdx.x >> 5;
    int t0 = (blockIdx.x & 31) << 8;

    {   // vectorized stage: interior at offset 8, halo 4 each side
        int ch = tid >> 5, q = tid & 31;
        const float* src = x1 + ((size_t)b*ORD + ch)*LEN + t0;
        float4 a0 = *reinterpret_cast<const float4*>(src + q*8);
        float4 a1 = *reinterpret_cast<const float4*>(src + q*8 + 4);
        *reinterpret_cast<float4*>(&xt[ch][8  + q*8]) = a0;
        *reinterpret_cast<float4*>(&xt[ch][12 + q*8]) = a1;
        if (q < 4) {                   // left: l = t0-4+q -> xt[4+q]
            int l = t0 - 4 + q;
            xt[ch][4 + q] = (l >= 0) ? src[q - 4] : 0.f;
        } else if (q < 8) {            // right: l = t0+256+(q-4) -> xt[260+q]
            int l = t0 + 256 + (q - 4);
            xt[ch][260 + q] = (l < LEN) ? src[256 + q - 4] : 0.f;
        }
    }

    if (tid < 9) {
        // each of 9 threads: fc (redundant) + its own k column
        const float Li = 1.0f / (float)LEN;
        float vw = P.p[17][0], vc = P.p[31][0];
#pragma unroll
        for (int ch = 0; ch < 8; ch++) {
            vw += P.p[16][ch] * (ws[96 +       b*8 + ch] * Li);
            vc += P.p[30][ch] * (ws[96 + 256 + b*8 + ch] * Li);
        }
        float width  = vw;
        float center = fminf(fmaxf(vc, 1.0f), 128.0f);

        float cst[7];
        cst[0] = 0.56418958354775628f;            // 1/sqrt(pi)
#pragma unroll
        for (int i = 1; i < 7; i++) cst[i] = cst[i-1] * sqrtf(2.0f / (float)i);

        int k = tid;
        float t = width * ((float)k - center);
        float e = expf(-0.5f * t * t);
        float hp = 1.0f, hc = 2.0f * t;
        kern[0][k] = e * cst[0];
        kern[1][k] = e * cst[1] * hc;
#pragma unroll
        for (int i = 2; i < 7; i++) {
            float hn = 2.0f*t*hc - 2.0f*(float)(i-1)*hp;
            hp = hc; hc = hn;
            kern[i][k] = e * cst[i] * hc;
        }
        kern[7][k] = 1.0f / (1.0f + expf(-2.0f * t));
    }
    __syncthreads();
    if (tid < 7) {                     // normalize rows 0..6 over k
        float ss = 0.f;
#pragma unroll
        for (int k = 0; k < 9; k++) ss += kern[tid][k]*kern[tid][k];
        float inv = 1.0f / fmaxf(sqrtf(ss), 1e-12f);
#pragma unroll
        for (int k = 0; k < 9; k++) kern[tid][k] *= inv;
    }
    __syncthreads();

    float acc = P.p[3][0];
#pragma unroll
    for (int c = 0; c < 8; c++) {
#pragma unroll
        for (int j = 0; j < 9; j++) acc += xt[c][4 + tid + j] * kern[c][j];
    }
    out[(size_t)b*LEN + t0 + tid] = acc;
}

// ---------------------------------------------------------------------------
extern "C" void kernel_launch(void* const* d_in, const int* in_sizes, int n_in,
                              void* d_out, int out_size, void* d_ws, size_t ws_size,
                              hipStream_t stream)
{
    (void)in_sizes; (void)n_in; (void)out_size; (void)ws_size;
    const float* x  = (const float*)d_in[0];
    const float* w1 = (const float*)d_in[1];
    const float* b1 = (const float*)d_in[2];
    float* outF = (float*)d_out;
    float* x1   = outF + (size_t)BATCH * LEN;   // second output region, reused
    float* ws   = (float*)d_ws;

    Params P;
    for (int i = 0; i < 32; i++) P.p[i] = (const float*)d_in[i];

    hipMemsetAsync(d_ws, 0, 4096, stream);
    k1_gemm_stats<<<512,  256, 0, stream>>>(x, w1, b1, x1, ws, P);
    k3_cpre_stats<<<512,  256, 0, stream>>>(x1, ws, P);
    k4_csum      <<<512,  256, 0, stream>>>(x1, ws, P);
    k6_out       <<<1024, 256, 0, stream>>>(x1, ws, P, outF);
}

// Round 4
// 133.457 us; speedup vs baseline: 3.3876x; 1.0686x over previous
//
#include <hip/hip_runtime.h>
#include <math.h>

#define BATCH 32
#define CIN   256
#define LEN   8192
#define HL    (LEN/2)
#define ORD   8
#define NPOS  (BATCH*LEN)   // 262144 positions

struct Params { const float* p[32]; };

// Input index map (setup_inputs dict order):
// 0 x, 1 conv1_w, 2 conv1_b, 3 conv2_b
// w_ branch: 4 c1w, 5 c1b, 6 c2w, 7 c2b, 8 g1, 9 g2, 10 g3, 11 b1, 12 b2,
//            13 b3, 14 pxw, 15 pxb, 16 fcw, 17 fcb        (c_ branch = +14)

// ws layout (floats):
// [0:32)   sum of conv pre-act, combo c = (br*2+conv)*8+ch
// [32:64)  sumsq of conv pre-act
// [64:80)  sum of c_pre (br*8+ch)
// [80:96)  sumsq of c_pre
// [96:608) per-sample sums of c: 96 + br*256 + b*8 + ch
// [1024:)  c_pre[16][NPOS]  (16.8 MB; ws observed ~1 GiB from poison fill)

// ---------------------------------------------------------------------------
// conv pre-activation pair (positions p, p+1) with weights read from GLOBAL
// via wave-uniform restrict pointer + compile-time offsets -> s_load (SMEM)
// ---------------------------------------------------------------------------
__device__ __forceinline__ void conv6_pair(
    const float xv[8][6], const float* __restrict__ w, float bv, int dil, int o,
    float& r0, float& r1)
{
    float a0 = bv, a1 = bv;
    const float* wr = w + o*24;      // weight layout [o][i][k]
#pragma unroll
    for (int i = 0; i < 8; i++) {
        float w0 = wr[i*3+0], w1 = wr[i*3+1], w2 = wr[i*3+2];
        if (dil == 1) {
            a0 += w0*xv[i][1] + w1*xv[i][2] + w2*xv[i][3];
            a1 += w0*xv[i][2] + w1*xv[i][3] + w2*xv[i][4];
        } else {
            a0 += w0*xv[i][0] + w1*xv[i][2] + w2*xv[i][4];
            a1 += w0*xv[i][1] + w1*xv[i][3] + w2*xv[i][5];
        }
    }
    r0 = a0; r1 = a1;
}

__device__ __forceinline__ void wave_reduce2(float& sv, float& sq)
{
#pragma unroll
    for (int m = 32; m >= 1; m >>= 1) {
        sv += __shfl_xor(sv, m, 64);
        sq += __shfl_xor(sq, m, 64);
    }
}
__device__ __forceinline__ void wave_reduce1(float& sv)
{
#pragma unroll
    for (int m = 32; m >= 1; m >>= 1) sv += __shfl_xor(sv, m, 64);
}

#define XT_W 520   // 2 pad + 2 halo + 512 interior + 2 halo + 2 pad
// window load: position pair (2*tid, 2*tid+1) needs xt[ch][2+2*tid .. 2+2*tid+5]
#define LOAD_XV6(xt, tid, xv)                                 \
    _Pragma("unroll")                                         \
    for (int i_ = 0; i_ < 8; i_++) {                          \
        _Pragma("unroll")                                     \
        for (int d_ = 0; d_ < 6; d_++)                        \
            xv[i_][d_] = xt[i_][2 + 2*(tid) + d_];            \
    }

// stage x1 tile [t0-2, t0+514) for 8 channels from global into xt
__device__ __forceinline__ void stage_tile(
    const float* __restrict__ x1, int b, int t0, float (*xt)[XT_W], int tid)
{
    int ch = tid >> 5, q = tid & 31;
    const float* src = x1 + ((size_t)b*ORD + ch)*LEN + t0 + q*16;
    float4* dst = reinterpret_cast<float4*>(&xt[ch][4 + q*16]);
#pragma unroll
    for (int j = 0; j < 4; j++) dst[j] = reinterpret_cast<const float4*>(src)[j];
    if (tid < 32) {
        int hc = tid >> 2, hh = tid & 3;
        int l   = t0 + ((hh < 2) ? (hh - 2) : (510 + hh));   // -2,-1,512,513
        int idx = (hh < 2) ? (2 + hh) : (514 + hh);          // 2,3,516,517
        xt[hc][idx] = ((unsigned)l < (unsigned)LEN)
                    ? x1[((size_t)b*ORD + hc)*LEN + l] : 0.f;
    }
}

// ---------------------------------------------------------------------------
// K1: pointwise GEMM -> x1 + bn1/bn2 stats (halo x prefetched into registers
// before the stream loop so its HBM latency hides under the GEMM)
// ---------------------------------------------------------------------------
__global__ __launch_bounds__(256, 2) void k1_gemm_stats(
    const float* __restrict__ x, const float* __restrict__ w,
    const float* __restrict__ bias, float* __restrict__ x1,
    float* __restrict__ ws,
    const float* __restrict__ wA, const float* __restrict__ bA,
    const float* __restrict__ wB, const float* __restrict__ bB,
    const float* __restrict__ wC, const float* __restrict__ bC,
    const float* __restrict__ wD, const float* __restrict__ bD)
{
    __shared__ float wt[CIN][ORD];   // wt[i][o]
    __shared__ float xt[8][XT_W];
    __shared__ float hbuf[4][257];   // halo x values, padded stride (bank-safe)
    __shared__ float part[256];
    int tid = threadIdx.x;
    for (int idx = tid; idx < CIN*ORD; idx += 256) {
        int o = idx >> 8, i = idx & 255;        // source layout [o][i]
        wt[i][o] = w[idx];
    }

    int b  = blockIdx.x >> 4;                   // 16 blocks per sample
    int t0 = (blockIdx.x & 15) << 9;            // 512 positions per block

    // issue halo x loads now; consumed after the main loop (latency hidden)
    const float* xch = x + ((size_t)b*CIN + tid)*LEN;
    float h0 = 0.f, h1 = 0.f, h2 = 0.f, h3 = 0.f;
    if (t0 >= 2)        { h0 = xch[t0-2];   h1 = xch[t0-1]; }
    if (t0 + 513 < LEN) { h2 = xch[t0+512]; h3 = xch[t0+513]; }
    __syncthreads();                            // wt ready

    const float2* xrow = reinterpret_cast<const float2*>(x)
                       + (size_t)b*CIN*HL + (t0 >> 1) + tid;
    float2 acc[ORD];
#pragma unroll
    for (int o = 0; o < ORD; o++) { acc[o].x = 0.f; acc[o].y = 0.f; }

#pragma unroll 8
    for (int i = 0; i < CIN; i++) {
        float2 xv2 = xrow[(size_t)i * HL];
        const float4* wr = reinterpret_cast<const float4*>(&wt[i][0]);
        float4 wa = wr[0], wb = wr[1];
        acc[0].x += xv2.x*wa.x; acc[0].y += xv2.y*wa.x;
        acc[1].x += xv2.x*wa.y; acc[1].y += xv2.y*wa.y;
        acc[2].x += xv2.x*wa.z; acc[2].y += xv2.y*wa.z;
        acc[3].x += xv2.x*wa.w; acc[3].y += xv2.y*wa.w;
        acc[4].x += xv2.x*wb.x; acc[4].y += xv2.y*wb.x;
        acc[5].x += xv2.x*wb.y; acc[5].y += xv2.y*wb.y;
        acc[6].x += xv2.x*wb.z; acc[6].y += xv2.y*wb.z;
        acc[7].x += xv2.x*wb.w; acc[7].y += xv2.y*wb.w;
    }

    float2* x1row = reinterpret_cast<float2*>(x1)
                  + (size_t)b*ORD*HL + (t0 >> 1) + tid;
#pragma unroll
    for (int o = 0; o < ORD; o++) {
        float bo = bias[o];
        float2 r; r.x = acc[o].x + bo; r.y = acc[o].y + bo;
        x1row[(size_t)o * HL] = r;
        *reinterpret_cast<float2*>(&xt[o][4 + 2*tid]) = r;
    }
    hbuf[0][tid] = h0; hbuf[1][tid] = h1; hbuf[2][tid] = h2; hbuf[3][tid] = h3;
    __syncthreads();

    // halo x1 positions t0-2, t0-1, t0+512, t0+513 from LDS-held x values
    if (tid < 32) {
        int hp = tid >> 3, ch = tid & 7;
        int l  = t0 + ((hp < 2) ? (hp - 2) : (510 + hp));
        float a = 0.f;
        if ((unsigned)l < (unsigned)LEN) {
            a = bias[ch];
#pragma unroll 8
            for (int i = 0; i < CIN; i++) a += hbuf[hp][i] * wt[i][ch];
        }
        int idx = (hp < 2) ? (2 + hp) : (514 + hp);
        xt[ch][idx] = a;
    }
    __syncthreads();

    float xv[8][6];
    LOAD_XV6(xt, tid, xv);

    int lane = tid & 63, wv = tid >> 6;
#pragma unroll
    for (int grp = 0; grp < 4; grp++) {
        const float* wg = (grp==0) ? wA : (grp==1) ? wB : (grp==2) ? wC : wD;
        const float* bg = (grp==0) ? bA : (grp==1) ? bB : (grp==2) ? bC : bD;
        int dil = (grp & 1) ? 2 : 1;
#pragma unroll
        for (int o = 0; o < 8; o++) {
            float a0, a1;
            conv6_pair(xv, wg, bg[o], dil, o, a0, a1);
            float sv = a0 + a1, sq = a0*a0 + a1*a1;
            wave_reduce2(sv, sq);
            if (lane == 0) {
                int c = grp*8 + o;
                part[c*4 + wv] = sv; part[(32+c)*4 + wv] = sq;
            }
        }
    }
    __syncthreads();
    if (tid < 64) {
        float s = part[tid*4] + part[tid*4+1] + part[tid*4+2] + part[tid*4+3];
        atomicAdd(&ws[tid], s);
    }
}

// ---------------------------------------------------------------------------
// K3: bn1/bn2+relu, pointwise conv -> c_pre (materialized); bn3 stats
// ---------------------------------------------------------------------------
__global__ __launch_bounds__(256, 2) void k3_cpre_stats(
    const float* __restrict__ x1,
    const float* __restrict__ wA, const float* __restrict__ bA,
    const float* __restrict__ wB, const float* __restrict__ bB,
    const float* __restrict__ wC, const float* __restrict__ bC,
    const float* __restrict__ wD, const float* __restrict__ bD,
    const float* __restrict__ pxA, const float* __restrict__ pxbA,
    const float* __restrict__ pxB, const float* __restrict__ pxbB,
    float* __restrict__ ws, float* __restrict__ cpre, Params P)
{
    __shared__ float scl[32], shf[32];
    __shared__ float xt[8][XT_W];
    __shared__ float part[128];
    int tid = threadIdx.x;
    if (tid >= 128 && tid < 160) {
        int c = tid - 128;
        int br = c >> 4, cv = (c >> 3) & 1, o = c & 7;
        const float Ninv = 1.0f / (float)NPOS;
        float m   = ws[c]      * Ninv;
        float var = ws[32 + c] * Ninv - m*m;
        const float* g  = P.p[ br ? (cv?23:22) : (cv?9:8)  ];
        const float* be = P.p[ br ? (cv?26:25) : (cv?12:11)];
        float sc = g[o] * rsqrtf(var + 1e-5f);
        scl[c] = sc; shf[c] = be[o] - m*sc;
    }
    int b  = blockIdx.x >> 4;
    int t0 = (blockIdx.x & 15) << 9;
    stage_tile(x1, b, t0, xt, tid);
    __syncthreads();

    float xv[8][6];
    LOAD_XV6(xt, tid, xv);

    int lane = tid & 63, wv = tid >> 6;
#pragma unroll
    for (int br = 0; br < 2; br++) {
        const float* w1p = br ? wC : wA;  const float* b1p = br ? bC : bA;
        const float* w2p = br ? wD : wB;  const float* b2p = br ? bD : bB;
        const float* pxp = br ? pxB : pxA;
        const float* pbp = br ? pxbB : pxbA;
        float s0[8], s1[8];
#pragma unroll
        for (int ch = 0; ch < 8; ch++) {
            int ca = (br*2+0)*8 + ch, cb = (br*2+1)*8 + ch;
            float a0, a1, c0, c1;
            conv6_pair(xv, w1p, b1p[ch], 1, ch, a0, a1);
            conv6_pair(xv, w2p, b2p[ch], 2, ch, c0, c1);
            s0[ch] = fmaxf(a0*scl[ca] + shf[ca], 0.f)
                   + fmaxf(c0*scl[cb] + shf[cb], 0.f);
            s1[ch] = fmaxf(a1*scl[ca] + shf[ca], 0.f)
                   + fmaxf(c1*scl[cb] + shf[cb], 0.f);
        }
#pragma unroll
        for (int o = 0; o < 8; o++) {
            float a0 = pbp[o], a1 = a0;
#pragma unroll
            for (int i = 0; i < 8; i++) {
                a0 += pxp[o*8 + i] * s0[i];
                a1 += pxp[o*8 + i] * s1[i];
            }
            int c = br*8 + o;
            float2 st; st.x = a0; st.y = a1;
            *reinterpret_cast<float2*>(
                &cpre[(size_t)c*NPOS + (size_t)b*LEN + t0 + 2*tid]) = st;
            float sv = a0 + a1, sq = a0*a0 + a1*a1;
            wave_reduce2(sv, sq);
            if (lane == 0) {
                part[c*4 + wv] = sv; part[(16+c)*4 + wv] = sq;
            }
        }
    }
    __syncthreads();
    if (tid < 32) {
        float s = part[tid*4] + part[tid*4+1] + part[tid*4+2] + part[tid*4+3];
        atomicAdd(&ws[64 + tid], s);
    }
}

// ---------------------------------------------------------------------------
// K4: light pass over c_pre -> relu(bn3) -> per-sample channel sums
// ---------------------------------------------------------------------------
__global__ __launch_bounds__(256) void k4_light(
    const float* __restrict__ cpre, float* __restrict__ ws, Params P)
{
    __shared__ float scl3[16], shf3[16];
    __shared__ float part[64];
    int tid = threadIdx.x;
    const float Ninv = 1.0f / (float)NPOS;
    if (tid < 16) {
        int br = tid >> 3, o = tid & 7;
        float m3 = ws[64 + tid] * Ninv;
        float v3 = ws[80 + tid] * Ninv - m3*m3;
        const float* g3 = P.p[ br ? 24 : 10 ];
        const float* b3 = P.p[ br ? 27 : 13 ];
        float sc = g3[o] * rsqrtf(v3 + 1e-5f);
        scl3[tid] = sc; shf3[tid] = b3[o] - m3*sc;
    }
    __syncthreads();

    int b  = blockIdx.x >> 4;
    int t0 = (blockIdx.x & 15) << 9;
    int lane = tid & 63, wv = tid >> 6;
#pragma unroll
    for (int c = 0; c < 16; c++) {
        float2 v = *reinterpret_cast<const float2*>(
            &cpre[(size_t)c*NPOS + (size_t)b*LEN + t0 + 2*tid]);
        float sv = fmaxf(v.x*scl3[c] + shf3[c], 0.f)
                 + fmaxf(v.y*scl3[c] + shf3[c], 0.f);
        wave_reduce1(sv);
        if (lane == 0) part[c*4 + wv] = sv;
    }
    __syncthreads();
    if (tid < 16) {
        float s = part[tid*4] + part[tid*4+1] + part[tid*4+2] + part[tid*4+3];
        atomicAdd(&ws[96 + (tid >> 3)*256 + b*8 + (tid & 7)], s);
    }
}

// ---------------------------------------------------------------------------
// K6: fc -> width/center -> Hermite kernel (parallel over k) -> 8x9 conv
// ---------------------------------------------------------------------------
#define XT6_W 272
__global__ __launch_bounds__(256) void k6_out(
    const float* __restrict__ x1, const float* __restrict__ ws, Params P,
    float* __restrict__ out)
{
    __shared__ float kern[8][9];
    __shared__ float xt[8][XT6_W];
    int tid = threadIdx.x;
    int b  = blockIdx.x >> 5;
    int t0 = (blockIdx.x & 31) << 8;

    {   // vectorized stage: interior at offset 8, halo 4 each side
        int ch = tid >> 5, q = tid & 31;
        const float* src = x1 + ((size_t)b*ORD + ch)*LEN + t0;
        float4 a0 = *reinterpret_cast<const float4*>(src + q*8);
        float4 a1 = *reinterpret_cast<const float4*>(src + q*8 + 4);
        *reinterpret_cast<float4*>(&xt[ch][8  + q*8]) = a0;
        *reinterpret_cast<float4*>(&xt[ch][12 + q*8]) = a1;
        if (q < 4) {                   // left: l = t0-4+q -> xt[4+q]
            int l = t0 - 4 + q;
            xt[ch][4 + q] = (l >= 0) ? src[q - 4] : 0.f;
        } else if (q < 8) {            // right: l = t0+256+(q-4) -> xt[260+q]
            int l = t0 + 256 + (q - 4);
            xt[ch][260 + q] = (l < LEN) ? src[256 + q - 4] : 0.f;
        }
    }

    if (tid < 9) {
        // each of 9 threads: fc (redundant) + its own k column
        const float Li = 1.0f / (float)LEN;
        float vw = P.p[17][0], vc = P.p[31][0];
#pragma unroll
        for (int ch = 0; ch < 8; ch++) {
            vw += P.p[16][ch] * (ws[96 +       b*8 + ch] * Li);
            vc += P.p[30][ch] * (ws[96 + 256 + b*8 + ch] * Li);
        }
        float width  = vw;
        float center = fminf(fmaxf(vc, 1.0f), 128.0f);

        float cst[7];
        cst[0] = 0.56418958354775628f;            // 1/sqrt(pi)
#pragma unroll
        for (int i = 1; i < 7; i++) cst[i] = cst[i-1] * sqrtf(2.0f / (float)i);

        int k = tid;
        float t = width * ((float)k - center);
        float e = expf(-0.5f * t * t);
        float hp = 1.0f, hc = 2.0f * t;
        kern[0][k] = e * cst[0];
        kern[1][k] = e * cst[1] * hc;
#pragma unroll
        for (int i = 2; i < 7; i++) {
            float hn = 2.0f*t*hc - 2.0f*(float)(i-1)*hp;
            hp = hc; hc = hn;
            kern[i][k] = e * cst[i] * hc;
        }
        kern[7][k] = 1.0f / (1.0f + expf(-2.0f * t));
    }
    __syncthreads();
    if (tid < 7) {                     // normalize rows 0..6 over k
        float ss = 0.f;
#pragma unroll
        for (int k = 0; k < 9; k++) ss += kern[tid][k]*kern[tid][k];
        float inv = 1.0f / fmaxf(sqrtf(ss), 1e-12f);
#pragma unroll
        for (int k = 0; k < 9; k++) kern[tid][k] *= inv;
    }
    __syncthreads();

    float acc = P.p[3][0];
#pragma unroll
    for (int c = 0; c < 8; c++) {
#pragma unroll
        for (int j = 0; j < 9; j++) acc += xt[c][4 + tid + j] * kern[c][j];
    }
    out[(size_t)b*LEN + t0 + tid] = acc;
}

// ---------------------------------------------------------------------------
extern "C" void kernel_launch(void* const* d_in, const int* in_sizes, int n_in,
                              void* d_out, int out_size, void* d_ws, size_t ws_size,
                              hipStream_t stream)
{
    (void)in_sizes; (void)n_in; (void)out_size; (void)ws_size;
    const float* x  = (const float*)d_in[0];
    const float* w1 = (const float*)d_in[1];
    const float* b1 = (const float*)d_in[2];
    float* outF = (float*)d_out;
    float* x1   = outF + (size_t)BATCH * LEN;   // second output region, reused
    float* ws   = (float*)d_ws;
    float* cpre = ws + 1024;                    // 16 x NPOS floats (16.8 MB)

    Params P;
    for (int i = 0; i < 32; i++) P.p[i] = (const float*)d_in[i];

    const float* wA = P.p[4],  *bA = P.p[5];
    const float* wB = P.p[6],  *bB = P.p[7];
    const float* wC = P.p[18], *bC = P.p[19];
    const float* wD = P.p[20], *bD = P.p[21];

    hipMemsetAsync(d_ws, 0, 4096, stream);
    k1_gemm_stats<<<512,  256, 0, stream>>>(x, w1, b1, x1, ws,
                                            wA, bA, wB, bB, wC, bC, wD, bD);
    k3_cpre_stats<<<512,  256, 0, stream>>>(x1, wA, bA, wB, bB, wC, bC, wD, bD,
                                            P.p[14], P.p[15], P.p[28], P.p[29],
                                            ws, cpre, P);
    k4_light     <<<512,  256, 0, stream>>>(cpre, ws, P);
    k6_out       <<<1024, 256, 0, stream>>>(x1, ws, P, outF);
}